// Round 12
// baseline (468.486 us; speedup 1.0000x reference)
//
#include <hip/hip_runtime.h>

#define N_NODES 50000
#define N_EDGES 800000
#define N_GRAPHS 256
#define HIDDEN 128
#define N_LAYERS 5
#define OUT_DIM 10
#define BN_EPS 1e-5f

#define BUCKET_SHIFT 7
#define BUCKET_NODES 128
#define N_BUCKETS ((N_NODES + BUCKET_NODES - 1) / BUCKET_NODES)  // 391
#define BUCKET_CAP 4096   // mean occupancy 2048, sd ~45 -> never overflows
#define POOL_BLKS ((N_NODES + 255) / 256)  // 196
#define AGG_BLKS (N_NODES / 4)             // 12500

#define STAGE_BLKS ((N_EDGES + 4095) / 4096)            // 196 (1024 thr, 4096 edges)
#define CVT_N4 (N_NODES * HIDDEN / 4)                   // 1600000 float4
#define CVT_BLKS1024 ((CVT_N4 + 1023) / 1024)           // 1563

typedef __bf16 bf16x8 __attribute__((ext_vector_type(8)));
typedef float f32x4 __attribute__((ext_vector_type(4)));

union FragAB {
    bf16x8 v;
    ushort s[8];
    uint4 q;
};

__device__ inline float bf2f(ushort u) {
    union { uint i; float f; } v;
    v.i = ((uint)u) << 16;
    return v.f;
}

__device__ inline float bf2f_lo(uint u) {
    union { uint i; float f; } v;
    v.i = u << 16;
    return v.f;
}

__device__ inline float bf2f_hi(uint u) {
    union { uint i; float f; } v;
    v.i = u & 0xffff0000u;
    return v.f;
}

__device__ inline ushort f2bf(float f) {
    union { float f; uint u; } v;
    v.f = f;
    uint b = v.u;
    uint r = (b + 0x7fffu + ((b >> 16) & 1u)) >> 16;  // RNE
    return (ushort)r;
}

// ---------------- setup: bucket-stage edges + cvt x + pack W (one grid) ----------------

__global__ __launch_bounds__(1024) void k_setup(const int* __restrict__ esrc,
                                                const int* __restrict__ edst,
                                                int* __restrict__ bcnt,
                                                uint* __restrict__ stage,
                                                const float* __restrict__ x,
                                                ushort* __restrict__ xb,
                                                const float* __restrict__ W1,
                                                const float* __restrict__ W2,
                                                ushort* __restrict__ Wp) {
    __shared__ int lcnt[N_BUCKETS];
    __shared__ int lbase[N_BUCKETS];
    int tid = threadIdx.x;
    int b = blockIdx.x;

    if (b < STAGE_BLKS) {
        for (int i = tid; i < N_BUCKETS; i += 1024) lcnt[i] = 0;
        __syncthreads();
        int e0 = b * 4096;
        uint pk[4];
        int bk[4];
        bool val[4];
#pragma unroll
        for (int i = 0; i < 4; ++i) {
            int e = e0 + i * 1024 + tid;
            val[i] = e < N_EDGES;
            bk[i] = 0;
            pk[i] = 0;
            if (val[i]) {
                int d = edst[e];
                int s = esrc[e];
                bk[i] = d >> BUCKET_SHIFT;
                pk[i] = (uint)s | ((uint)(d & (BUCKET_NODES - 1)) << 16);
                atomicAdd(&lcnt[bk[i]], 1);
            }
        }
        __syncthreads();
        for (int i = tid; i < N_BUCKETS; i += 1024) {
            int c = lcnt[i];
            lbase[i] = c ? atomicAdd(&bcnt[i], c) : 0;
            lcnt[i] = 0;
        }
        __syncthreads();
#pragma unroll
        for (int i = 0; i < 4; ++i) {
            if (val[i]) {
                int pos = lbase[bk[i]] + atomicAdd(&lcnt[bk[i]], 1);
                if (pos < BUCKET_CAP)
                    stage[(size_t)bk[i] * BUCKET_CAP + pos] = pk[i];
            }
        }
    } else if (b < STAGE_BLKS + CVT_BLKS1024) {
        int i = (b - STAGE_BLKS) * 1024 + tid;
        if (i < CVT_N4) {
            float4 v = ((const float4*)x)[i];
            ushort4 o;
            o.x = f2bf(v.x); o.y = f2bf(v.y); o.z = f2bf(v.z); o.w = f2bf(v.w);
            ((ushort4*)xb)[i] = o;
        }
    } else {
        int mat = b - STAGE_BLKS - CVT_BLKS1024;  // 0..9
        const float* src = (mat < 5) ? (W1 + (size_t)mat * 16384)
                                     : (W2 + (size_t)(mat - 5) * 16384);
        ushort* dst = Wp + (size_t)mat * 16384;
        for (int idx = tid; idx < 16384; idx += 1024) {
            int jj = idx & 7;
            int frag = idx >> 3;
            int lane = frag & 63;
            int cf = frag >> 6;
            int ct = cf >> 2, kc = cf & 3;
            int k = kc * 32 + (lane >> 4) * 8 + jj;
            int c = (lane & 15) * 8 + ct;
            dst[idx] = f2bf(src[k * 128 + c]);
        }
    }
}

// ---------------- fill: per-bucket node histogram + scan + scatter ----------------
// noff[v] = absStart | (count << 21);  absStart < 391*4096 = 1601536 < 2^21.

__global__ __launch_bounds__(256) void k_fill3(const uint* __restrict__ stage,
                                               const int* __restrict__ bcnt,
                                               ushort* __restrict__ adj,
                                               uint* __restrict__ noff) {
    __shared__ int cnt[BUCKET_NODES];
    __shared__ int scn[BUCKET_NODES];
    __shared__ int cur[BUCKET_NODES];
    int bk = blockIdx.x;
    int tid = threadIdx.x;
    int total = bcnt[bk];
    if (total > BUCKET_CAP) total = BUCKET_CAP;
    const uint* st = stage + (size_t)bk * BUCKET_CAP;

    if (tid < BUCKET_NODES) cnt[tid] = 0;
    __syncthreads();
    for (int i = tid; i < total; i += 256)
        atomicAdd(&cnt[st[i] >> 16], 1);
    __syncthreads();
    if (tid < BUCKET_NODES) scn[tid] = cnt[tid];
    __syncthreads();
    for (int off = 1; off < BUCKET_NODES; off <<= 1) {
        int t = (tid < BUCKET_NODES && tid >= off) ? scn[tid - off] : 0;
        __syncthreads();
        if (tid < BUCKET_NODES) scn[tid] += t;
        __syncthreads();
    }
    if (tid < BUCKET_NODES) {
        int start = scn[tid] - cnt[tid];  // exclusive
        cur[tid] = start;
        int node = bk * BUCKET_NODES + tid;
        if (node < N_NODES)
            noff[node] = (uint)(bk * BUCKET_CAP + start) | ((uint)cnt[tid] << 21);
    }
    __syncthreads();
    for (int i = tid; i < total; i += 256) {
        uint pk = st[i];
        int pos = atomicAdd(&cur[pk >> 16], 1);
        adj[(size_t)bk * BUCKET_CAP + pos] = (ushort)(pk & 0xffffu);
    }
}

// ---------------- gather core (deep issue, degree-classed) ----------------
// deg is wave-uniform (one node per wave) -> the class branch is convergent.

#define ACC8_BN(T)                                                  \
    {                                                               \
        float f0 = bf2f_lo(T.x), f1 = bf2f_hi(T.x);                 \
        float f2 = bf2f_lo(T.y), f3 = bf2f_hi(T.y);                 \
        float f4 = bf2f_lo(T.z), f5 = bf2f_hi(T.z);                 \
        float f6 = bf2f_lo(T.w), f7 = bf2f_hi(T.w);                 \
        if (BN) {                                                   \
            f0 = fmaxf(f0 * sc[0] + sh[0], 0.f);                    \
            f1 = fmaxf(f1 * sc[1] + sh[1], 0.f);                    \
            f2 = fmaxf(f2 * sc[2] + sh[2], 0.f);                    \
            f3 = fmaxf(f3 * sc[3] + sh[3], 0.f);                    \
            f4 = fmaxf(f4 * sc[4] + sh[4], 0.f);                    \
            f5 = fmaxf(f5 * sc[5] + sh[5], 0.f);                    \
            f6 = fmaxf(f6 * sc[6] + sh[6], 0.f);                    \
            f7 = fmaxf(f7 * sc[7] + sh[7], 0.f);                    \
        }                                                           \
        a0 += f0; a1 += f1; a2 += f2; a3 += f3;                     \
        a4 += f4; a5 += f5; a6 += f6; a7 += f7;                     \
    }

template <bool BN>
__device__ inline void agg_one_node(int v, const uint4* __restrict__ h4,
                                    const uint* __restrict__ noff,
                                    const ushort* __restrict__ adj,
                                    ushort* __restrict__ y,
                                    int e, int c16,
                                    const float* sc, const float* sh) {
    uint pkoff = noff[v];
    int off = (int)(pkoff & 0x1FFFFFu);
    int deg = (int)(pkoff >> 21);
    int end = off + deg;

    float a0 = 0.f, a1 = 0.f, a2 = 0.f, a3 = 0.f;
    float a4 = 0.f, a5 = 0.f, a6 = 0.f, a7 = 0.f;

    if (deg <= 16) {
        // 4 concurrent gather blocks (covers <=16 edges) -- ~54% of nodes
        int u[4];
        bool val[4];
#pragma unroll
        for (int k = 0; k < 4; ++k) {
            int idx = off + k * 4 + e;
            val[k] = idx < end;
            u[k] = adj[val[k] ? idx : off];
        }
        uint4 t[4];
#pragma unroll
        for (int k = 0; k < 4; ++k)
            t[k] = h4[(size_t)u[k] * 16 + c16];
#pragma unroll
        for (int k = 0; k < 4; ++k) {
            if (val[k]) ACC8_BN(t[k])
        }
    } else {
        // 8 concurrent gather blocks (covers <=32 edges) + rare tail
        int u[8];
        bool val[8];
#pragma unroll
        for (int k = 0; k < 8; ++k) {
            int idx = off + k * 4 + e;
            val[k] = idx < end;
            u[k] = adj[val[k] ? idx : off];
        }
        uint4 t[8];
#pragma unroll
        for (int k = 0; k < 8; ++k)
            t[k] = h4[(size_t)u[k] * 16 + c16];
#pragma unroll
        for (int k = 0; k < 8; ++k) {
            if (val[k]) ACC8_BN(t[k])
        }
        for (int j = off + 32; j < end; j += 4) {
            bool valid = (j + e) < end;
            int uu = adj[valid ? (j + e) : off];
            uint4 tt = h4[(size_t)uu * 16 + c16];
            if (valid) ACC8_BN(tt)
        }
    }

    a0 += __shfl_xor(a0, 16, 64); a0 += __shfl_xor(a0, 32, 64);
    a1 += __shfl_xor(a1, 16, 64); a1 += __shfl_xor(a1, 32, 64);
    a2 += __shfl_xor(a2, 16, 64); a2 += __shfl_xor(a2, 32, 64);
    a3 += __shfl_xor(a3, 16, 64); a3 += __shfl_xor(a3, 32, 64);
    a4 += __shfl_xor(a4, 16, 64); a4 += __shfl_xor(a4, 32, 64);
    a5 += __shfl_xor(a5, 16, 64); a5 += __shfl_xor(a5, 32, 64);
    a6 += __shfl_xor(a6, 16, 64); a6 += __shfl_xor(a6, 32, 64);
    a7 += __shfl_xor(a7, 16, 64); a7 += __shfl_xor(a7, 32, 64);
    if (e == 0) {
        uint4 self = h4[(size_t)v * 16 + c16];
        ACC8_BN(self)
        uint4 pk;
        pk.x = (uint)f2bf(a0) | ((uint)f2bf(a1) << 16);
        pk.y = (uint)f2bf(a2) | ((uint)f2bf(a3) << 16);
        pk.z = (uint)f2bf(a4) | ((uint)f2bf(a5) << 16);
        pk.w = (uint)f2bf(a6) | ((uint)f2bf(a7) << 16);
        ((uint4*)y)[(size_t)v * 16 + c16] = pk;
    }
}

// layer 0: plain gather of x
__global__ __launch_bounds__(256) void k_agg_first(const ushort* __restrict__ h,
                                                   const uint* __restrict__ noff,
                                                   const ushort* __restrict__ adj,
                                                   ushort* __restrict__ y) {
    int wave = threadIdx.x >> 6;
    int lane = threadIdx.x & 63;
    int v = blockIdx.x * 4 + wave;
    agg_one_node<false>(v, (const uint4*)h, noff, adj, y,
                        lane >> 4, lane & 15, nullptr, nullptr);
}

// layers 1..4: pool(l-1) [blocks 0..POOL_BLKS) + BN-fused gather(l) [rest]
__global__ __launch_bounds__(256) void k_aggpool(const ushort* __restrict__ z2,
                                                 const float* __restrict__ statIn,
                                                 const float* __restrict__ g,
                                                 const float* __restrict__ b,
                                                 const int* __restrict__ batch,
                                                 float* __restrict__ pooled,
                                                 const uint* __restrict__ noff,
                                                 const ushort* __restrict__ adj,
                                                 ushort* __restrict__ y) {
    int tid = threadIdx.x;
    int w = tid >> 6, lane = tid & 63;

    if (blockIdx.x >= POOL_BLKS) {
        __shared__ float scs[128];
        __shared__ float shs[128];
        if (tid < 128) {
            float s = 0.f, q = 0.f;
#pragma unroll
            for (int sl = 0; sl < 8; ++sl) {
                s += statIn[sl * 256 + tid];
                q += statIn[sl * 256 + 128 + tid];
            }
            float mn = s * (1.f / N_NODES);
            float var = q * (1.f / N_NODES) - mn * mn;
            float scv = g[tid] * rsqrtf(var + BN_EPS);
            scs[tid] = scv;
            shs[tid] = b[tid] - mn * scv;
        }
        __syncthreads();
        int c16 = lane & 15;
        float sc[8], sh[8];
#pragma unroll
        for (int j = 0; j < 8; ++j) {
            sc[j] = scs[c16 * 8 + j];
            sh[j] = shs[c16 * 8 + j];
        }
        int v = (blockIdx.x - POOL_BLKS) * 4 + w;
        agg_one_node<true>(v, (const uint4*)z2, noff, adj, y,
                           lane >> 4, c16, sc, sh);
        return;
    }

    // pool path
    int c0 = lane * 2;
    float s0 = 0.f, q0 = 0.f, s1 = 0.f, q1 = 0.f;
#pragma unroll
    for (int sl = 0; sl < 8; ++sl) {
        s0 += statIn[sl * 256 + c0];
        q0 += statIn[sl * 256 + 128 + c0];
        s1 += statIn[sl * 256 + c0 + 1];
        q1 += statIn[sl * 256 + 128 + c0 + 1];
    }
    float mn0 = s0 * (1.f / N_NODES);
    float var0 = q0 * (1.f / N_NODES) - mn0 * mn0;
    float sc0 = g[c0] * rsqrtf(var0 + BN_EPS);
    float sh0 = b[c0] - mn0 * sc0;
    float mn1 = s1 * (1.f / N_NODES);
    float var1 = q1 * (1.f / N_NODES) - mn1 * mn1;
    float sc1 = g[c0 + 1] * rsqrtf(var1 + BN_EPS);
    float sh1 = b[c0 + 1] - mn1 * sc1;

    int r0 = blockIdx.x * 256 + w * 64;
    int r1 = r0 + 64;
    if (r1 > N_NODES) r1 = N_NODES;
    if (r0 >= N_NODES) return;

    int bidx = r0 + lane;
    int myb = batch[bidx < N_NODES ? bidx : (N_NODES - 1)];

    float a0 = 0.f, a1 = 0.f;
    int curg = -1;
    const uint* z1 = (const uint*)z2;
    for (int r = r0; r < r1; ++r) {
        uint t = z1[(size_t)r * 64 + lane];
        float v0 = fmaxf(bf2f((ushort)(t & 0xffff)) * sc0 + sh0, 0.f);
        float v1 = fmaxf(bf2f((ushort)(t >> 16)) * sc1 + sh1, 0.f);
        int gg = __shfl(myb, r - r0, 64);
        if (gg != curg) {
            if (curg >= 0) {
                atomicAdd(&pooled[(size_t)curg * 640 + c0], a0);
                atomicAdd(&pooled[(size_t)curg * 640 + c0 + 1], a1);
            }
            a0 = 0.f; a1 = 0.f;
            curg = gg;
        }
        a0 += v0;
        a1 += v1;
    }
    if (curg >= 0) {
        atomicAdd(&pooled[(size_t)curg * 640 + c0], a0);
        atomicAdd(&pooled[(size_t)curg * 640 + c0 + 1], a1);
    }
}

// standalone pool for the last layer
__global__ __launch_bounds__(256) void k_pool(const ushort* __restrict__ z2,
                                              const float* __restrict__ statIn,
                                              const float* __restrict__ g,
                                              const float* __restrict__ b,
                                              const int* __restrict__ batch,
                                              float* __restrict__ pooled) {
    int w = threadIdx.x >> 6, lane = threadIdx.x & 63;
    int c0 = lane * 2;
    float s0 = 0.f, q0 = 0.f, s1 = 0.f, q1 = 0.f;
#pragma unroll
    for (int sl = 0; sl < 8; ++sl) {
        s0 += statIn[sl * 256 + c0];
        q0 += statIn[sl * 256 + 128 + c0];
        s1 += statIn[sl * 256 + c0 + 1];
        q1 += statIn[sl * 256 + 128 + c0 + 1];
    }
    float mn0 = s0 * (1.f / N_NODES);
    float var0 = q0 * (1.f / N_NODES) - mn0 * mn0;
    float sc0 = g[c0] * rsqrtf(var0 + BN_EPS);
    float sh0 = b[c0] - mn0 * sc0;
    float mn1 = s1 * (1.f / N_NODES);
    float var1 = q1 * (1.f / N_NODES) - mn1 * mn1;
    float sc1 = g[c0 + 1] * rsqrtf(var1 + BN_EPS);
    float sh1 = b[c0 + 1] - mn1 * sc1;

    int r0 = blockIdx.x * 256 + w * 64;
    int r1 = r0 + 64;
    if (r1 > N_NODES) r1 = N_NODES;
    if (r0 >= N_NODES) return;

    int bidx = r0 + lane;
    int myb = batch[bidx < N_NODES ? bidx : (N_NODES - 1)];

    float a0 = 0.f, a1 = 0.f;
    int curg = -1;
    const uint* z1 = (const uint*)z2;
    for (int r = r0; r < r1; ++r) {
        uint t = z1[(size_t)r * 64 + lane];
        float v0 = fmaxf(bf2f((ushort)(t & 0xffff)) * sc0 + sh0, 0.f);
        float v1 = fmaxf(bf2f((ushort)(t >> 16)) * sc1 + sh1, 0.f);
        int gg = __shfl(myb, r - r0, 64);
        if (gg != curg) {
            if (curg >= 0) {
                atomicAdd(&pooled[(size_t)curg * 640 + c0], a0);
                atomicAdd(&pooled[(size_t)curg * 640 + c0 + 1], a1);
            }
            a0 = 0.f; a1 = 0.f;
            curg = gg;
        }
        a0 += v0;
        a1 += v1;
    }
    if (curg >= 0) {
        atomicAdd(&pooled[(size_t)curg * 640 + c0], a0);
        atomicAdd(&pooled[(size_t)curg * 640 + c0 + 1], a1);
    }
}

// ---------------- MFMA GEMM: direct global frag loads + direct coalesced store ----------------

template <bool ACT>
__global__ __launch_bounds__(256) void k_gemm(const ushort* __restrict__ A,
                                              const ushort* __restrict__ Wp,
                                              const float* __restrict__ bias,
                                              const float* __restrict__ g,
                                              const float* __restrict__ b,
                                              const float* __restrict__ statIn,
                                              ushort* __restrict__ Z,
                                              float* __restrict__ statOut) {
    __shared__ float scs[128];
    __shared__ float shs[128];
    __shared__ float redS[4][128];
    __shared__ float redQ[4][128];

    int tid = threadIdx.x;
    int w = tid >> 6, lane = tid & 63;
    int m = lane & 15, quad = lane >> 4;
    int r0 = blockIdx.x * 64;

    if (ACT) {
        if (tid < 128) {
            float s = 0.f, q = 0.f;
#pragma unroll
            for (int sl = 0; sl < 8; ++sl) {
                s += statIn[sl * 256 + tid];
                q += statIn[sl * 256 + 128 + tid];
            }
            float mn = s * (1.f / N_NODES);
            float var = q * (1.f / N_NODES) - mn * mn;
            float sc = g[tid] * rsqrtf(var + BN_EPS);
            scs[tid] = sc;
            shs[tid] = b[tid] - mn * sc;
        }
        __syncthreads();
    }

    int arow = r0 + w * 16 + m;
    if (arow >= N_NODES) arow = N_NODES - 1;

    f32x4 acc[8];
#pragma unroll
    for (int ct = 0; ct < 8; ++ct) acc[ct] = (f32x4){0.f, 0.f, 0.f, 0.f};

    const uint4* Wp4 = (const uint4*)Wp;

#pragma unroll
    for (int kc = 0; kc < 4; ++kc) {
        FragAB a;
        a.q = *(const uint4*)(A + (size_t)arow * 128 + kc * 32 + quad * 8);
        if (ACT) {
            int k0 = kc * 32 + quad * 8;
#pragma unroll
            for (int jj = 0; jj < 8; ++jj) {
                float fv = bf2f(a.s[jj]);
                fv = fmaxf(fv * scs[k0 + jj] + shs[k0 + jj], 0.f);
                a.s[jj] = f2bf(fv);
            }
        }
#pragma unroll
        for (int ct = 0; ct < 8; ++ct) {
            FragAB bf;
            bf.q = Wp4[(ct * 4 + kc) * 64 + lane];
            acc[ct] = __builtin_amdgcn_mfma_f32_16x16x32_bf16(a.v, bf.v, acc[ct], 0, 0, 0);
        }
    }

    int rbase = r0 + w * 16 + quad * 4;
    float bc[8];
#pragma unroll
    for (int ct = 0; ct < 8; ++ct) bc[ct] = bias[m * 8 + ct];

    float st[8], sq[8];
#pragma unroll
    for (int ct = 0; ct < 8; ++ct) { st[ct] = 0.f; sq[ct] = 0.f; }

#pragma unroll
    for (int i = 0; i < 4; ++i) {
        int row = rbase + i;
        if (row < N_NODES) {
            float v[8];
#pragma unroll
            for (int ct = 0; ct < 8; ++ct) {
                v[ct] = acc[ct][i] + bc[ct];
                st[ct] += v[ct];
                sq[ct] += v[ct] * v[ct];
            }
            uint4 pk;
            pk.x = (uint)f2bf(v[0]) | ((uint)f2bf(v[1]) << 16);
            pk.y = (uint)f2bf(v[2]) | ((uint)f2bf(v[3]) << 16);
            pk.z = (uint)f2bf(v[4]) | ((uint)f2bf(v[5]) << 16);
            pk.w = (uint)f2bf(v[6]) | ((uint)f2bf(v[7]) << 16);
            *(uint4*)(Z + (size_t)row * 128 + m * 8) = pk;
        }
    }
#pragma unroll
    for (int ct = 0; ct < 8; ++ct) {
        st[ct] += __shfl_xor(st[ct], 16, 64);
        st[ct] += __shfl_xor(st[ct], 32, 64);
        sq[ct] += __shfl_xor(sq[ct], 16, 64);
        sq[ct] += __shfl_xor(sq[ct], 32, 64);
    }
    if (quad == 0) {
#pragma unroll
        for (int ct = 0; ct < 8; ++ct) {
            redS[w][m * 8 + ct] = st[ct];
            redQ[w][m * 8 + ct] = sq[ct];
        }
    }
    __syncthreads();
    if (tid < 128) {
        float s = redS[0][tid] + redS[1][tid] + redS[2][tid] + redS[3][tid];
        float q = redQ[0][tid] + redQ[1][tid] + redQ[2][tid] + redQ[3][tid];
        int slot = (blockIdx.x & 7) * 256;
        atomicAdd(&statOut[slot + tid], s);
        atomicAdd(&statOut[slot + 128 + tid], q);
    }
}

// ---------------- final MLP ----------------

__global__ __launch_bounds__(128) void k_mlp(const float* __restrict__ pooled,
                                             const float* __restrict__ fc1W,
                                             const float* __restrict__ fc1b,
                                             const float* __restrict__ fc2W,
                                             const float* __restrict__ fc2b,
                                             float* __restrict__ out) {
    __shared__ float p[640];
    __shared__ float hid[128];
    int g = blockIdx.x;
    int t = threadIdx.x;
    for (int i = t; i < 640; i += 128) p[i] = pooled[(size_t)g * 640 + i];
    __syncthreads();
    float a = fc1b[t];
    for (int k = 0; k < 640; ++k) a += p[k] * fc1W[(size_t)k * 128 + t];
    hid[t] = fmaxf(a, 0.f);
    __syncthreads();
    if (t < OUT_DIM) {
        float o = fc2b[t];
#pragma unroll 8
        for (int c = 0; c < 128; ++c) o += hid[c] * fc2W[(size_t)c * OUT_DIM + t];
        out[(size_t)g * OUT_DIM + t] = o;
    }
}

// ---------------- host ----------------

static inline char* align256(char* p) {
    return (char*)(((uintptr_t)p + 255) & ~(uintptr_t)255);
}

extern "C" void kernel_launch(void* const* d_in, const int* in_sizes, int n_in,
                              void* d_out, int out_size, void* d_ws, size_t ws_size,
                              hipStream_t stream) {
    const float* x    = (const float*)d_in[0];
    const float* W1   = (const float*)d_in[1];
    const float* b1   = (const float*)d_in[2];
    const float* bng1 = (const float*)d_in[3];
    const float* bnb1 = (const float*)d_in[4];
    const float* W2   = (const float*)d_in[5];
    const float* b2   = (const float*)d_in[6];
    const float* bng2 = (const float*)d_in[7];
    const float* bnb2 = (const float*)d_in[8];
    const float* fc1W = (const float*)d_in[9];
    const float* fc1b = (const float*)d_in[10];
    const float* fc2W = (const float*)d_in[11];
    const float* fc2b = (const float*)d_in[12];
    const int* ei     = (const int*)d_in[13];
    const int* batch  = (const int*)d_in[14];
    const int* esrc = ei;
    const int* edst = ei + N_EDGES;

    const size_t NF = (size_t)N_NODES * HIDDEN;
    char* p = (char*)d_ws;
    ushort* ybf  = (ushort*)p; p = align256(p + NF * 2);   // agg out
    ushort* z1bf = (ushort*)p; p = align256(p + NF * 2);
    ushort* z2bf = (ushort*)p; p = align256(p + NF * 2);
    ushort* xbf  = (ushort*)p; p = align256(p + NF * 2);
    ushort* Wp   = (ushort*)p; p = align256(p + (size_t)10 * 16384 * 2);
    // one contiguous memset region: pooled + stats + bcnt
    float* pooled = (float*)p; p += (size_t)N_GRAPHS * 640 * 4;
    float* stats  = (float*)p; p += (size_t)10 * 8 * 256 * 4;
    int* bcnt     = (int*)p; p = align256(p + (size_t)N_BUCKETS * 4);
    uint* noff    = (uint*)p; p = align256(p + (size_t)N_NODES * 4);
    ushort* adj   = (ushort*)p; p = align256(p + (size_t)N_BUCKETS * BUCKET_CAP * 2);
    uint* stage   = (uint*)p; p = align256(p + (size_t)N_BUCKETS * BUCKET_CAP * 4);

    hipMemsetAsync(pooled, 0,
                   ((size_t)N_GRAPHS * 640 + (size_t)10 * 8 * 256) * 4 + (size_t)N_BUCKETS * 4,
                   stream);

    k_setup<<<STAGE_BLKS + CVT_BLKS1024 + 10, 1024, 0, stream>>>(
        esrc, edst, bcnt, stage, x, xbf, W1, W2, Wp);
    k_fill3<<<N_BUCKETS, 256, 0, stream>>>(stage, bcnt, adj, noff);

    const int GEMM_BLKS = (N_NODES + 63) / 64;  // 782
    for (int l = 0; l < N_LAYERS; ++l) {
        float* st1 = stats + (size_t)(2 * l) * 2048;
        float* st2 = stats + (size_t)(2 * l + 1) * 2048;

        if (l == 0) {
            k_agg_first<<<AGG_BLKS, 256, 0, stream>>>(xbf, noff, adj, ybf);
        } else {
            float* st2prev = stats + (size_t)(2 * l - 1) * 2048;
            k_aggpool<<<POOL_BLKS + AGG_BLKS, 256, 0, stream>>>(
                z2bf, st2prev, bng2 + (l - 1) * 128, bnb2 + (l - 1) * 128,
                batch, pooled + (l - 1) * 128, noff, adj, ybf);
        }

        k_gemm<false><<<GEMM_BLKS, 256, 0, stream>>>(
            ybf, Wp + (size_t)l * 16384, b1 + l * 128,
            nullptr, nullptr, nullptr, z1bf, st1);

        k_gemm<true><<<GEMM_BLKS, 256, 0, stream>>>(
            z1bf, Wp + (size_t)(5 + l) * 16384, b2 + l * 128,
            bng1 + l * 128, bnb1 + l * 128, st1, z2bf, st2);
    }

    k_pool<<<POOL_BLKS, 256, 0, stream>>>(
        z2bf, stats + (size_t)(2 * N_LAYERS - 1) * 2048,
        bng2 + (N_LAYERS - 1) * 128, bnb2 + (N_LAYERS - 1) * 128,
        batch, pooled + (N_LAYERS - 1) * 128);

    k_mlp<<<N_GRAPHS, 128, 0, stream>>>(pooled, fc1W, fc1b, fc2W, fc2b, (float*)d_out);
}

// Round 14
// 461.815 us; speedup vs baseline: 1.0144x; 1.0144x over previous
//
#include <hip/hip_runtime.h>

#define N_NODES 50000
#define N_EDGES 800000
#define N_GRAPHS 256
#define HIDDEN 128
#define N_LAYERS 5
#define OUT_DIM 10
#define BN_EPS 1e-5f

#define BUCKET_SHIFT 7
#define BUCKET_NODES 128
#define N_BUCKETS ((N_NODES + BUCKET_NODES - 1) / BUCKET_NODES)  // 391
#define BUCKET_CAP 4096   // mean occupancy 2048, sd ~45 -> never overflows
#define POOL_BLKS ((N_NODES + 255) / 256)  // 196
#define AGG_BLKS (N_NODES / 4)             // 12500

#define STAGE_BLKS ((N_EDGES + 4095) / 4096)            // 196 (1024 thr, 4096 edges)
#define CVT_N4 (N_NODES * HIDDEN / 4)                   // 1600000 float4
#define CVT_BLKS1024 ((CVT_N4 + 1023) / 1024)           // 1563

typedef __bf16 bf16x8 __attribute__((ext_vector_type(8)));
typedef float f32x4 __attribute__((ext_vector_type(4)));

union FragAB {
    bf16x8 v;
    ushort s[8];
    uint4 q;
};

__device__ inline float bf2f(ushort u) {
    union { uint i; float f; } v;
    v.i = ((uint)u) << 16;
    return v.f;
}

__device__ inline float bf2f_lo(uint u) {
    union { uint i; float f; } v;
    v.i = u << 16;
    return v.f;
}

__device__ inline float bf2f_hi(uint u) {
    union { uint i; float f; } v;
    v.i = u & 0xffff0000u;
    return v.f;
}

__device__ inline ushort f2bf(float f) {
    union { float f; uint u; } v;
    v.f = f;
    uint b = v.u;
    uint r = (b + 0x7fffu + ((b >> 16) & 1u)) >> 16;  // RNE
    return (ushort)r;
}

// ---------------- setup: bucket-stage edges + cvt x + pack W (one grid) ----------------

__global__ __launch_bounds__(1024) void k_setup(const int* __restrict__ esrc,
                                                const int* __restrict__ edst,
                                                int* __restrict__ bcnt,
                                                uint* __restrict__ stage,
                                                const float* __restrict__ x,
                                                ushort* __restrict__ xb,
                                                const float* __restrict__ W1,
                                                const float* __restrict__ W2,
                                                ushort* __restrict__ Wp) {
    __shared__ int lcnt[N_BUCKETS];
    __shared__ int lbase[N_BUCKETS];
    int tid = threadIdx.x;
    int b = blockIdx.x;

    if (b < STAGE_BLKS) {
        for (int i = tid; i < N_BUCKETS; i += 1024) lcnt[i] = 0;
        __syncthreads();
        int e0 = b * 4096;
        uint pk[4];
        int bk[4];
        bool val[4];
#pragma unroll
        for (int i = 0; i < 4; ++i) {
            int e = e0 + i * 1024 + tid;
            val[i] = e < N_EDGES;
            bk[i] = 0;
            pk[i] = 0;
            if (val[i]) {
                int d = edst[e];
                int s = esrc[e];
                bk[i] = d >> BUCKET_SHIFT;
                pk[i] = (uint)s | ((uint)(d & (BUCKET_NODES - 1)) << 16);
                atomicAdd(&lcnt[bk[i]], 1);
            }
        }
        __syncthreads();
        for (int i = tid; i < N_BUCKETS; i += 1024) {
            int c = lcnt[i];
            lbase[i] = c ? atomicAdd(&bcnt[i], c) : 0;
            lcnt[i] = 0;
        }
        __syncthreads();
#pragma unroll
        for (int i = 0; i < 4; ++i) {
            if (val[i]) {
                int pos = lbase[bk[i]] + atomicAdd(&lcnt[bk[i]], 1);
                if (pos < BUCKET_CAP)
                    stage[(size_t)bk[i] * BUCKET_CAP + pos] = pk[i];
            }
        }
    } else if (b < STAGE_BLKS + CVT_BLKS1024) {
        int i = (b - STAGE_BLKS) * 1024 + tid;
        if (i < CVT_N4) {
            float4 v = ((const float4*)x)[i];
            ushort4 o;
            o.x = f2bf(v.x); o.y = f2bf(v.y); o.z = f2bf(v.z); o.w = f2bf(v.w);
            ((ushort4*)xb)[i] = o;
        }
    } else {
        int mat = b - STAGE_BLKS - CVT_BLKS1024;  // 0..9
        const float* src = (mat < 5) ? (W1 + (size_t)mat * 16384)
                                     : (W2 + (size_t)(mat - 5) * 16384);
        ushort* dst = Wp + (size_t)mat * 16384;
        for (int idx = tid; idx < 16384; idx += 1024) {
            int jj = idx & 7;
            int frag = idx >> 3;
            int lane = frag & 63;
            int cf = frag >> 6;
            int ct = cf >> 2, kc = cf & 3;
            int k = kc * 32 + (lane >> 4) * 8 + jj;
            int c = (lane & 15) * 8 + ct;
            dst[idx] = f2bf(src[k * 128 + c]);
        }
    }
}

// ---------------- fill: per-bucket node histogram + scan + scatter ----------------
// noff[v] = absStart | (count << 21);  absStart < 391*4096 = 1601536 < 2^21.

__global__ __launch_bounds__(256) void k_fill3(const uint* __restrict__ stage,
                                               const int* __restrict__ bcnt,
                                               ushort* __restrict__ adj,
                                               uint* __restrict__ noff) {
    __shared__ int cnt[BUCKET_NODES];
    __shared__ int scn[BUCKET_NODES];
    __shared__ int cur[BUCKET_NODES];
    int bk = blockIdx.x;
    int tid = threadIdx.x;
    int total = bcnt[bk];
    if (total > BUCKET_CAP) total = BUCKET_CAP;
    const uint* st = stage + (size_t)bk * BUCKET_CAP;

    if (tid < BUCKET_NODES) cnt[tid] = 0;
    __syncthreads();
    for (int i = tid; i < total; i += 256)
        atomicAdd(&cnt[st[i] >> 16], 1);
    __syncthreads();
    if (tid < BUCKET_NODES) scn[tid] = cnt[tid];
    __syncthreads();
    for (int off = 1; off < BUCKET_NODES; off <<= 1) {
        int t = (tid < BUCKET_NODES && tid >= off) ? scn[tid - off] : 0;
        __syncthreads();
        if (tid < BUCKET_NODES) scn[tid] += t;
        __syncthreads();
    }
    if (tid < BUCKET_NODES) {
        int start = scn[tid] - cnt[tid];  // exclusive
        cur[tid] = start;
        int node = bk * BUCKET_NODES + tid;
        if (node < N_NODES)
            noff[node] = (uint)(bk * BUCKET_CAP + start) | ((uint)cnt[tid] << 21);
    }
    __syncthreads();
    for (int i = tid; i < total; i += 256) {
        uint pk = st[i];
        int pos = atomicAdd(&cur[pk >> 16], 1);
        adj[(size_t)bk * BUCKET_CAP + pos] = (ushort)(pk & 0xffffu);
    }
}

// ---------------- gather core (deep issue, degree-classed) ----------------
// deg is wave-uniform (one node per wave) -> the class branch is convergent.

#define ACC8_BN(T)                                                  \
    {                                                               \
        float f0 = bf2f_lo(T.x), f1 = bf2f_hi(T.x);                 \
        float f2 = bf2f_lo(T.y), f3 = bf2f_hi(T.y);                 \
        float f4 = bf2f_lo(T.z), f5 = bf2f_hi(T.z);                 \
        float f6 = bf2f_lo(T.w), f7 = bf2f_hi(T.w);                 \
        if (BN) {                                                   \
            f0 = fmaxf(f0 * sc[0] + sh[0], 0.f);                    \
            f1 = fmaxf(f1 * sc[1] + sh[1], 0.f);                    \
            f2 = fmaxf(f2 * sc[2] + sh[2], 0.f);                    \
            f3 = fmaxf(f3 * sc[3] + sh[3], 0.f);                    \
            f4 = fmaxf(f4 * sc[4] + sh[4], 0.f);                    \
            f5 = fmaxf(f5 * sc[5] + sh[5], 0.f);                    \
            f6 = fmaxf(f6 * sc[6] + sh[6], 0.f);                    \
            f7 = fmaxf(f7 * sc[7] + sh[7], 0.f);                    \
        }                                                           \
        a0 += f0; a1 += f1; a2 += f2; a3 += f3;                     \
        a4 += f4; a5 += f5; a6 += f6; a7 += f7;                     \
    }

template <bool BN>
__device__ inline void agg_one_node(int v, const uint4* __restrict__ h4,
                                    const uint* __restrict__ noff,
                                    const ushort* __restrict__ adj,
                                    ushort* __restrict__ y,
                                    int e, int c16,
                                    const float* sc, const float* sh) {
    uint pkoff = noff[v];
    int off = (int)(pkoff & 0x1FFFFFu);
    int deg = (int)(pkoff >> 21);
    int end = off + deg;

    float a0 = 0.f, a1 = 0.f, a2 = 0.f, a3 = 0.f;
    float a4 = 0.f, a5 = 0.f, a6 = 0.f, a7 = 0.f;

    if (deg <= 16) {
        // 4 concurrent gather blocks (covers <=16 edges) -- ~54% of nodes
        int u[4];
        bool val[4];
#pragma unroll
        for (int k = 0; k < 4; ++k) {
            int idx = off + k * 4 + e;
            val[k] = idx < end;
            u[k] = adj[val[k] ? idx : off];
        }
        uint4 t[4];
#pragma unroll
        for (int k = 0; k < 4; ++k)
            t[k] = h4[(size_t)u[k] * 16 + c16];
#pragma unroll
        for (int k = 0; k < 4; ++k) {
            if (val[k]) ACC8_BN(t[k])
        }
    } else {
        // 8 concurrent gather blocks (covers <=32 edges) + rare tail
        int u[8];
        bool val[8];
#pragma unroll
        for (int k = 0; k < 8; ++k) {
            int idx = off + k * 4 + e;
            val[k] = idx < end;
            u[k] = adj[val[k] ? idx : off];
        }
        uint4 t[8];
#pragma unroll
        for (int k = 0; k < 8; ++k)
            t[k] = h4[(size_t)u[k] * 16 + c16];
#pragma unroll
        for (int k = 0; k < 8; ++k) {
            if (val[k]) ACC8_BN(t[k])
        }
        for (int j = off + 32; j < end; j += 4) {
            bool valid = (j + e) < end;
            int uu = adj[valid ? (j + e) : off];
            uint4 tt = h4[(size_t)uu * 16 + c16];
            if (valid) ACC8_BN(tt)
        }
    }

    a0 += __shfl_xor(a0, 16, 64); a0 += __shfl_xor(a0, 32, 64);
    a1 += __shfl_xor(a1, 16, 64); a1 += __shfl_xor(a1, 32, 64);
    a2 += __shfl_xor(a2, 16, 64); a2 += __shfl_xor(a2, 32, 64);
    a3 += __shfl_xor(a3, 16, 64); a3 += __shfl_xor(a3, 32, 64);
    a4 += __shfl_xor(a4, 16, 64); a4 += __shfl_xor(a4, 32, 64);
    a5 += __shfl_xor(a5, 16, 64); a5 += __shfl_xor(a5, 32, 64);
    a6 += __shfl_xor(a6, 16, 64); a6 += __shfl_xor(a6, 32, 64);
    a7 += __shfl_xor(a7, 16, 64); a7 += __shfl_xor(a7, 32, 64);
    if (e == 0) {
        uint4 self = h4[(size_t)v * 16 + c16];
        ACC8_BN(self)
        uint4 pk;
        pk.x = (uint)f2bf(a0) | ((uint)f2bf(a1) << 16);
        pk.y = (uint)f2bf(a2) | ((uint)f2bf(a3) << 16);
        pk.z = (uint)f2bf(a4) | ((uint)f2bf(a5) << 16);
        pk.w = (uint)f2bf(a6) | ((uint)f2bf(a7) << 16);
        ((uint4*)y)[(size_t)v * 16 + c16] = pk;
    }
}

// layer 0: plain gather of x
__global__ __launch_bounds__(256) void k_agg_first(const ushort* __restrict__ h,
                                                   const uint* __restrict__ noff,
                                                   const ushort* __restrict__ adj,
                                                   ushort* __restrict__ y) {
    int wave = threadIdx.x >> 6;
    int lane = threadIdx.x & 63;
    int v = blockIdx.x * 4 + wave;
    agg_one_node<false>(v, (const uint4*)h, noff, adj, y,
                        lane >> 4, lane & 15, nullptr, nullptr);
}

// layers 1..4: pool(l-1) [blocks 0..POOL_BLKS) + BN-fused gather(l) [rest]
__global__ __launch_bounds__(256) void k_aggpool(const ushort* __restrict__ z2,
                                                 const float* __restrict__ statIn,
                                                 const float* __restrict__ g,
                                                 const float* __restrict__ b,
                                                 const int* __restrict__ batch,
                                                 float* __restrict__ pooled,
                                                 const uint* __restrict__ noff,
                                                 const ushort* __restrict__ adj,
                                                 ushort* __restrict__ y) {
    int tid = threadIdx.x;
    int w = tid >> 6, lane = tid & 63;

    if (blockIdx.x >= POOL_BLKS) {
        __shared__ float scs[128];
        __shared__ float shs[128];
        if (tid < 128) {
            float s = 0.f, q = 0.f;
#pragma unroll
            for (int sl = 0; sl < 8; ++sl) {
                s += statIn[sl * 256 + tid];
                q += statIn[sl * 256 + 128 + tid];
            }
            float mn = s * (1.f / N_NODES);
            float var = q * (1.f / N_NODES) - mn * mn;
            float scv = g[tid] * rsqrtf(var + BN_EPS);
            scs[tid] = scv;
            shs[tid] = b[tid] - mn * scv;
        }
        __syncthreads();
        int c16 = lane & 15;
        float sc[8], sh[8];
#pragma unroll
        for (int j = 0; j < 8; ++j) {
            sc[j] = scs[c16 * 8 + j];
            sh[j] = shs[c16 * 8 + j];
        }
        int v = (blockIdx.x - POOL_BLKS) * 4 + w;
        agg_one_node<true>(v, (const uint4*)z2, noff, adj, y,
                           lane >> 4, c16, sc, sh);
        return;
    }

    // pool path
    int c0 = lane * 2;
    float s0 = 0.f, q0 = 0.f, s1 = 0.f, q1 = 0.f;
#pragma unroll
    for (int sl = 0; sl < 8; ++sl) {
        s0 += statIn[sl * 256 + c0];
        q0 += statIn[sl * 256 + 128 + c0];
        s1 += statIn[sl * 256 + c0 + 1];
        q1 += statIn[sl * 256 + 128 + c0 + 1];
    }
    float mn0 = s0 * (1.f / N_NODES);
    float var0 = q0 * (1.f / N_NODES) - mn0 * mn0;
    float sc0 = g[c0] * rsqrtf(var0 + BN_EPS);
    float sh0 = b[c0] - mn0 * sc0;
    float mn1 = s1 * (1.f / N_NODES);
    float var1 = q1 * (1.f / N_NODES) - mn1 * mn1;
    float sc1 = g[c0 + 1] * rsqrtf(var1 + BN_EPS);
    float sh1 = b[c0 + 1] - mn1 * sc1;

    int r0 = blockIdx.x * 256 + w * 64;
    int r1 = r0 + 64;
    if (r1 > N_NODES) r1 = N_NODES;
    if (r0 >= N_NODES) return;

    int bidx = r0 + lane;
    int myb = batch[bidx < N_NODES ? bidx : (N_NODES - 1)];

    float a0 = 0.f, a1 = 0.f;
    int curg = -1;
    const uint* z1 = (const uint*)z2;
    for (int r = r0; r < r1; ++r) {
        uint t = z1[(size_t)r * 64 + lane];
        float v0 = fmaxf(bf2f((ushort)(t & 0xffff)) * sc0 + sh0, 0.f);
        float v1 = fmaxf(bf2f((ushort)(t >> 16)) * sc1 + sh1, 0.f);
        int gg = __shfl(myb, r - r0, 64);
        if (gg != curg) {
            if (curg >= 0) {
                atomicAdd(&pooled[(size_t)curg * 640 + c0], a0);
                atomicAdd(&pooled[(size_t)curg * 640 + c0 + 1], a1);
            }
            a0 = 0.f; a1 = 0.f;
            curg = gg;
        }
        a0 += v0;
        a1 += v1;
    }
    if (curg >= 0) {
        atomicAdd(&pooled[(size_t)curg * 640 + c0], a0);
        atomicAdd(&pooled[(size_t)curg * 640 + c0 + 1], a1);
    }
}

// standalone pool for the last layer
__global__ __launch_bounds__(256) void k_pool(const ushort* __restrict__ z2,
                                              const float* __restrict__ statIn,
                                              const float* __restrict__ g,
                                              const float* __restrict__ b,
                                              const int* __restrict__ batch,
                                              float* __restrict__ pooled) {
    int w = threadIdx.x >> 6, lane = threadIdx.x & 63;
    int c0 = lane * 2;
    float s0 = 0.f, q0 = 0.f, s1 = 0.f, q1 = 0.f;
#pragma unroll
    for (int sl = 0; sl < 8; ++sl) {
        s0 += statIn[sl * 256 + c0];
        q0 += statIn[sl * 256 + 128 + c0];
        s1 += statIn[sl * 256 + c0 + 1];
        q1 += statIn[sl * 256 + 128 + c0 + 1];
    }
    float mn0 = s0 * (1.f / N_NODES);
    float var0 = q0 * (1.f / N_NODES) - mn0 * mn0;
    float sc0 = g[c0] * rsqrtf(var0 + BN_EPS);
    float sh0 = b[c0] - mn0 * sc0;
    float mn1 = s1 * (1.f / N_NODES);
    float var1 = q1 * (1.f / N_NODES) - mn1 * mn1;
    float sc1 = g[c0 + 1] * rsqrtf(var1 + BN_EPS);
    float sh1 = b[c0 + 1] - mn1 * sc1;

    int r0 = blockIdx.x * 256 + w * 64;
    int r1 = r0 + 64;
    if (r1 > N_NODES) r1 = N_NODES;
    if (r0 >= N_NODES) return;

    int bidx = r0 + lane;
    int myb = batch[bidx < N_NODES ? bidx : (N_NODES - 1)];

    float a0 = 0.f, a1 = 0.f;
    int curg = -1;
    const uint* z1 = (const uint*)z2;
    for (int r = r0; r < r1; ++r) {
        uint t = z1[(size_t)r * 64 + lane];
        float v0 = fmaxf(bf2f((ushort)(t & 0xffff)) * sc0 + sh0, 0.f);
        float v1 = fmaxf(bf2f((ushort)(t >> 16)) * sc1 + sh1, 0.f);
        int gg = __shfl(myb, r - r0, 64);
        if (gg != curg) {
            if (curg >= 0) {
                atomicAdd(&pooled[(size_t)curg * 640 + c0], a0);
                atomicAdd(&pooled[(size_t)curg * 640 + c0 + 1], a1);
            }
            a0 = 0.f; a1 = 0.f;
            curg = gg;
        }
        a0 += v0;
        a1 += v1;
    }
    if (curg >= 0) {
        atomicAdd(&pooled[(size_t)curg * 640 + c0], a0);
        atomicAdd(&pooled[(size_t)curg * 640 + c0 + 1], a1);
    }
}

// ---------------- MFMA GEMM: direct global frag loads + direct coalesced store ----------------

template <bool ACT>
__global__ __launch_bounds__(256) void k_gemm(const ushort* __restrict__ A,
                                              const ushort* __restrict__ Wp,
                                              const float* __restrict__ bias,
                                              const float* __restrict__ g,
                                              const float* __restrict__ b,
                                              const float* __restrict__ statIn,
                                              ushort* __restrict__ Z,
                                              float* __restrict__ statOut) {
    __shared__ float scs[128];
    __shared__ float shs[128];
    __shared__ float redS[4][128];
    __shared__ float redQ[4][128];

    int tid = threadIdx.x;
    int w = tid >> 6, lane = tid & 63;
    int m = lane & 15, quad = lane >> 4;
    int r0 = blockIdx.x * 64;

    if (ACT) {
        if (tid < 128) {
            float s = 0.f, q = 0.f;
#pragma unroll
            for (int sl = 0; sl < 8; ++sl) {
                s += statIn[sl * 256 + tid];
                q += statIn[sl * 256 + 128 + tid];
            }
            float mn = s * (1.f / N_NODES);
            float var = q * (1.f / N_NODES) - mn * mn;
            float sc = g[tid] * rsqrtf(var + BN_EPS);
            scs[tid] = sc;
            shs[tid] = b[tid] - mn * sc;
        }
        __syncthreads();
    }

    int arow = r0 + w * 16 + m;
    if (arow >= N_NODES) arow = N_NODES - 1;

    f32x4 acc[8];
#pragma unroll
    for (int ct = 0; ct < 8; ++ct) acc[ct] = (f32x4){0.f, 0.f, 0.f, 0.f};

    const uint4* Wp4 = (const uint4*)Wp;

#pragma unroll
    for (int kc = 0; kc < 4; ++kc) {
        FragAB a;
        a.q = *(const uint4*)(A + (size_t)arow * 128 + kc * 32 + quad * 8);
        if (ACT) {
            int k0 = kc * 32 + quad * 8;
#pragma unroll
            for (int jj = 0; jj < 8; ++jj) {
                float fv = bf2f(a.s[jj]);
                fv = fmaxf(fv * scs[k0 + jj] + shs[k0 + jj], 0.f);
                a.s[jj] = f2bf(fv);
            }
        }
#pragma unroll
        for (int ct = 0; ct < 8; ++ct) {
            FragAB bf;
            bf.q = Wp4[(ct * 4 + kc) * 64 + lane];
            acc[ct] = __builtin_amdgcn_mfma_f32_16x16x32_bf16(a.v, bf.v, acc[ct], 0, 0, 0);
        }
    }

    int rbase = r0 + w * 16 + quad * 4;
    float bc[8];
#pragma unroll
    for (int ct = 0; ct < 8; ++ct) bc[ct] = bias[m * 8 + ct];

    float st[8], sq[8];
#pragma unroll
    for (int ct = 0; ct < 8; ++ct) { st[ct] = 0.f; sq[ct] = 0.f; }

#pragma unroll
    for (int i = 0; i < 4; ++i) {
        int row = rbase + i;
        if (row < N_NODES) {
            float v[8];
#pragma unroll
            for (int ct = 0; ct < 8; ++ct) {
                v[ct] = acc[ct][i] + bc[ct];
                st[ct] += v[ct];
                sq[ct] += v[ct] * v[ct];
            }
            uint4 pk;
            pk.x = (uint)f2bf(v[0]) | ((uint)f2bf(v[1]) << 16);
            pk.y = (uint)f2bf(v[2]) | ((uint)f2bf(v[3]) << 16);
            pk.z = (uint)f2bf(v[4]) | ((uint)f2bf(v[5]) << 16);
            pk.w = (uint)f2bf(v[6]) | ((uint)f2bf(v[7]) << 16);
            *(uint4*)(Z + (size_t)row * 128 + m * 8) = pk;
        }
    }
#pragma unroll
    for (int ct = 0; ct < 8; ++ct) {
        st[ct] += __shfl_xor(st[ct], 16, 64);
        st[ct] += __shfl_xor(st[ct], 32, 64);
        sq[ct] += __shfl_xor(sq[ct], 16, 64);
        sq[ct] += __shfl_xor(sq[ct], 32, 64);
    }
    if (quad == 0) {
#pragma unroll
        for (int ct = 0; ct < 8; ++ct) {
            redS[w][m * 8 + ct] = st[ct];
            redQ[w][m * 8 + ct] = sq[ct];
        }
    }
    __syncthreads();
    if (tid < 128) {
        float s = redS[0][tid] + redS[1][tid] + redS[2][tid] + redS[3][tid];
        float q = redQ[0][tid] + redQ[1][tid] + redQ[2][tid] + redQ[3][tid];
        int slot = (blockIdx.x & 7) * 256;
        atomicAdd(&statOut[slot + tid], s);
        atomicAdd(&statOut[slot + 128 + tid], q);
    }
}

// ---------------- final MLP ----------------

__global__ __launch_bounds__(128) void k_mlp(const float* __restrict__ pooled,
                                             const float* __restrict__ fc1W,
                                             const float* __restrict__ fc1b,
                                             const float* __restrict__ fc2W,
                                             const float* __restrict__ fc2b,
                                             float* __restrict__ out) {
    __shared__ float p[640];
    __shared__ float hid[128];
    int g = blockIdx.x;
    int t = threadIdx.x;
    for (int i = t; i < 640; i += 128) p[i] = pooled[(size_t)g * 640 + i];
    __syncthreads();
    float a = fc1b[t];
    for (int k = 0; k < 640; ++k) a += p[k] * fc1W[(size_t)k * 128 + t];
    hid[t] = fmaxf(a, 0.f);
    __syncthreads();
    if (t < OUT_DIM) {
        float o = fc2b[t];
#pragma unroll 8
        for (int c = 0; c < 128; ++c) o += hid[c] * fc2W[(size_t)c * OUT_DIM + t];
        out[(size_t)g * OUT_DIM + t] = o;
    }
}

// ---------------- host ----------------

static inline char* align256(char* p) {
    return (char*)(((uintptr_t)p + 255) & ~(uintptr_t)255);
}

extern "C" void kernel_launch(void* const* d_in, const int* in_sizes, int n_in,
                              void* d_out, int out_size, void* d_ws, size_t ws_size,
                              hipStream_t stream) {
    const float* x    = (const float*)d_in[0];
    const float* W1   = (const float*)d_in[1];
    const float* b1   = (const float*)d_in[2];
    const float* bng1 = (const float*)d_in[3];
    const float* bnb1 = (const float*)d_in[4];
    const float* W2   = (const float*)d_in[5];
    const float* b2   = (const float*)d_in[6];
    const float* bng2 = (const float*)d_in[7];
    const float* bnb2 = (const float*)d_in[8];
    const float* fc1W = (const float*)d_in[9];
    const float* fc1b = (const float*)d_in[10];
    const float* fc2W = (const float*)d_in[11];
    const float* fc2b = (const float*)d_in[12];
    const int* ei     = (const int*)d_in[13];
    const int* batch  = (const int*)d_in[14];
    const int* esrc = ei;
    const int* edst = ei + N_EDGES;

    const size_t NF = (size_t)N_NODES * HIDDEN;
    char* p = (char*)d_ws;
    ushort* ybf  = (ushort*)p; p = align256(p + NF * 2);   // agg out
    ushort* z1bf = (ushort*)p; p = align256(p + NF * 2);
    ushort* z2bf = (ushort*)p; p = align256(p + NF * 2);
    ushort* xbf  = (ushort*)p; p = align256(p + NF * 2);
    ushort* Wp   = (ushort*)p; p = align256(p + (size_t)10 * 16384 * 2);
    // one contiguous memset region: pooled + stats + bcnt
    float* pooled = (float*)p; p += (size_t)N_GRAPHS * 640 * 4;
    float* stats  = (float*)p; p += (size_t)10 * 8 * 256 * 4;
    int* bcnt     = (int*)p; p = align256(p + (size_t)N_BUCKETS * 4);
    uint* noff    = (uint*)p; p = align256(p + (size_t)N_NODES * 4);
    ushort* adj   = (ushort*)p; p = align256(p + (size_t)N_BUCKETS * BUCKET_CAP * 2);
    uint* stage   = (uint*)p; p = align256(p + (size_t)N_BUCKETS * BUCKET_CAP * 4);

    hipMemsetAsync(pooled, 0,
                   ((size_t)N_GRAPHS * 640 + (size_t)10 * 8 * 256) * 4 + (size_t)N_BUCKETS * 4,
                   stream);

    k_setup<<<STAGE_BLKS + CVT_BLKS1024 + 10, 1024, 0, stream>>>(
        esrc, edst, bcnt, stage, x, xbf, W1, W2, Wp);
    k_fill3<<<N_BUCKETS, 256, 0, stream>>>(stage, bcnt, adj, noff);

    const int GEMM_BLKS = (N_NODES + 63) / 64;  // 782
    for (int l = 0; l < N_LAYERS; ++l) {
        float* st1 = stats + (size_t)(2 * l) * 2048;
        float* st2 = stats + (size_t)(2 * l + 1) * 2048;

        if (l == 0) {
            k_agg_first<<<AGG_BLKS, 256, 0, stream>>>(xbf, noff, adj, ybf);
        } else {
            float* st2prev = stats + (size_t)(2 * l - 1) * 2048;
            k_aggpool<<<POOL_BLKS + AGG_BLKS, 256, 0, stream>>>(
                z2bf, st2prev, bng2 + (l - 1) * 128, bnb2 + (l - 1) * 128,
                batch, pooled + (l - 1) * 128, noff, adj, ybf);
        }

        k_gemm<false><<<GEMM_BLKS, 256, 0, stream>>>(
            ybf, Wp + (size_t)l * 16384, b1 + l * 128,
            nullptr, nullptr, nullptr, z1bf, st1);

        k_gemm<true><<<GEMM_BLKS, 256, 0, stream>>>(
            z1bf, Wp + (size_t)(5 + l) * 16384, b2 + l * 128,
            bng1 + l * 128, bnb1 + l * 128, st1, z2bf, st2);
    }

    k_pool<<<POOL_BLKS, 256, 0, stream>>>(
        z2bf, stats + (size_t)(2 * N_LAYERS - 1) * 2048,
        bng2 + (N_LAYERS - 1) * 128, bnb2 + (N_LAYERS - 1) * 128,
        batch, pooled + (N_LAYERS - 1) * 128);

    k_mlp<<<N_GRAPHS, 128, 0, stream>>>(pooled, fc1W, fc1b, fc2W, fc2b, (float*)d_out);
}